// Round 1
// baseline (42.387 us; speedup 1.0000x reference)
//
#include <hip/hip_runtime.h>
#include <stdint.h>

// Problem constants (fixed by setup_inputs: bs=8, n=4096, c=256, pool=1024)
#define BATCH 8
#define NPTS  4096
#define CH    256
#define QN    1024
#define WAVES_PER_BLOCK 16
#define BLOCK (WAVES_PER_BLOCK * 64)          // 1024 threads
#define BLOCKS_PER_BATCH (QN / WAVES_PER_BLOCK) // 64

__device__ __forceinline__ float fmul(float a, float b) { return __fmul_rn(a, b); }
__device__ __forceinline__ float fadd(float a, float b) { return __fadd_rn(a, b); }

__device__ __forceinline__ void cswap(uint64_t& lo, uint64_t& hi) {
  uint64_t mn = hi < lo ? hi : lo;
  uint64_t mx = hi < lo ? lo : hi;
  lo = mn; hi = mx;
}

__global__ __launch_bounds__(BLOCK) void knn_pool_kernel(
    const float* __restrict__ verts,   // [BATCH, NPTS, 3]
    const float* __restrict__ feat,    // [BATCH, NPTS, CH]
    const int*   __restrict__ sidx,    // [QN]
    float* __restrict__ outV,          // [BATCH, QN, 3]
    float* __restrict__ outF)          // [BATCH, QN, CH]
{
  extern __shared__ float4 sv[];       // NPTS * 16B = 64 KB: x,y,z,|v|^2

  const int batch = blockIdx.x / BLOCKS_PER_BATCH;
  const int qblk  = blockIdx.x % BLOCKS_PER_BATCH;
  const float* vb = verts + (size_t)batch * (NPTS * 3);

  // ---- stage vertices + squared norm into LDS ----
  for (int c = threadIdx.x; c < NPTS; c += BLOCK) {
    float x = vb[c * 3 + 0];
    float y = vb[c * 3 + 1];
    float z = vb[c * 3 + 2];
    // quad = (x*x + y*y) + z*z, no FMA contraction (match numpy/jax op order)
    float q = fadd(fadd(fmul(x, x), fmul(y, y)), fmul(z, z));
    sv[c] = make_float4(x, y, z, q);
  }
  __syncthreads();

  const int wave = threadIdx.x >> 6;
  const int lane = threadIdx.x & 63;
  const int i = qblk * WAVES_PER_BLOCK + wave;   // query slot in [0, QN)
  const int n = sidx[i];                          // vertex index of this query
  const float4 vq = sv[n];

  // ---- per-lane sorted top-5 of key = (ordered(dist)<<32) | candidate ----
  uint64_t a0 = ~0ull, a1 = ~0ull, a2 = ~0ull, a3 = ~0ull, a4 = ~0ull;
#pragma unroll 8
  for (int c = lane; c < NPTS; c += 64) {
    float4 v = sv[c];
    // inner = (xq*xc + yq*yc) + zq*zc   (reference einsum order, no fma)
    float dot = fadd(fadd(fmul(vq.x, v.x), fmul(vq.y, v.y)), fmul(vq.z, v.z));
    // d = ((-2*inner) + quad_m) + quad_n  (reference broadcast order)
    float d = fadd(fadd(fmul(-2.0f, dot), v.w), vq.w);
    uint32_t bb = __float_as_uint(d);
    bb ^= (uint32_t)((int32_t)bb >> 31) | 0x80000000u;   // order-preserving map
    uint64_t key = ((uint64_t)bb << 32) | (uint32_t)c;
    a4 = key < a4 ? key : a4;     // evict largest if new key smaller
    cswap(a3, a4);
    cswap(a2, a3);
    cswap(a1, a2);
    cswap(a0, a1);
  }

  // ---- wave merge: 5 rounds of "min key strictly greater than prev" ----
  uint64_t prev = 0;
  uint64_t nb1, nb2, nb3, nb4;
#pragma unroll
  for (int r = 0; r < 5; ++r) {
    uint64_t cand = a0 > prev ? a0
                  : a1 > prev ? a1
                  : a2 > prev ? a2
                  : a3 > prev ? a3
                  : a4 > prev ? a4 : ~0ull;
#pragma unroll
    for (int s = 32; s >= 1; s >>= 1) {
      uint64_t o = (uint64_t)__shfl_xor((long long)cand, s, 64);
      if (o < cand) cand = o;
    }
    // r==0 is self (distance exactly 0) -> dropped, like reference [:, :, 1:]
    if (r == 1) nb1 = cand;
    if (r == 2) nb2 = cand;
    if (r == 3) nb3 = cand;
    if (r == 4) nb4 = cand;
    prev = cand;
  }

  const int n1 = (int)(uint32_t)nb1;
  const int n2 = (int)(uint32_t)nb2;
  const int n3 = (int)(uint32_t)nb3;
  const int n4 = (int)(uint32_t)nb4;

  // ---- gather 4 feature rows, max-pool, store ----
  const float* fb = feat + (size_t)batch * NPTS * CH;
  const int col = lane * 4;   // 64 lanes * 4 = 256 channels
  float4 f1 = *(const float4*)(fb + (size_t)n1 * CH + col);
  float4 f2 = *(const float4*)(fb + (size_t)n2 * CH + col);
  float4 f3 = *(const float4*)(fb + (size_t)n3 * CH + col);
  float4 f4 = *(const float4*)(fb + (size_t)n4 * CH + col);
  float4 r;
  r.x = fmaxf(fmaxf(f1.x, f2.x), fmaxf(f3.x, f4.x));
  r.y = fmaxf(fmaxf(f1.y, f2.y), fmaxf(f3.y, f4.y));
  r.z = fmaxf(fmaxf(f1.z, f2.z), fmaxf(f3.z, f4.z));
  r.w = fmaxf(fmaxf(f1.w, f2.w), fmaxf(f3.w, f4.w));
  *(float4*)(outF + ((size_t)batch * QN + i) * CH + col) = r;

  // ---- vertices_pool copy ----
  if (lane < 3) {
    outV[((size_t)batch * QN + i) * 3 + lane] = vb[(size_t)n * 3 + lane];
  }
}

extern "C" void kernel_launch(void* const* d_in, const int* in_sizes, int n_in,
                              void* d_out, int out_size, void* d_ws, size_t ws_size,
                              hipStream_t stream) {
  const float* verts = (const float*)d_in[0];
  const float* feat  = (const float*)d_in[1];
  const int*   sidx  = (const int*)d_in[2];
  float* outV = (float*)d_out;                          // [BATCH, QN, 3]
  float* outF = (float*)d_out + (size_t)BATCH * QN * 3; // [BATCH, QN, CH]

  dim3 grid(BATCH * BLOCKS_PER_BATCH);   // 512 blocks
  dim3 block(BLOCK);                     // 1024 threads (16 waves)
  size_t lds_bytes = (size_t)NPTS * sizeof(float4);  // 64 KB
  knn_pool_kernel<<<grid, block, lds_bytes, stream>>>(verts, feat, sidx, outV, outF);
}